// Round 5
// baseline (240.208 us; speedup 1.0000x reference)
//
#include <hip/hip_runtime.h>
#include <stdint.h>

// PRNG layout: partitionable counter-mode, bits = y0 ^ y1 (verified round 1)

#define NB 8
#define NT 4096
#define ND 512
#define NH 512
#define NTOK (NB * NT)

typedef __attribute__((ext_vector_type(8))) short short8;
typedef __attribute__((ext_vector_type(4))) float f32x4;

// ---- workspace layout (bytes) ----
#define WS_WEX   0          // 512*2 f64   : W_embed @ Wx
#define WS_PEX   8192       // 4096*2 f64  : (b_embed + pe[t]) @ Wx
#define WS_VWV   73728      // 2*8*2 f64   : v_i @ Wv
#define WS_KEYS  73984      // 4 u32       : fold_in keys
#define WS_DIV   74000      // 256 f64     : div table exp(2f * c)
#define WS_SEL   207120     // NTOK i32
#define WS_LENS  338192     // 8 i32
#define WS_WT    338224     // 512*512 u16 : bf16 W_embed transposed [n][k]
#define WS_APACK 1048576    // 8*4096*512 u16 : packed selected rows (bf16)
#define WS_DD    1048576    // 32768*2 f64 : dot results (dead before Apack written)

__device__ inline void threefry2x32(uint32_t k0, uint32_t k1, uint32_t x0, uint32_t x1,
                                    uint32_t& y0, uint32_t& y1) {
  uint32_t ks2 = k0 ^ k1 ^ 0x1BD11BDAu;
  x0 += k0; x1 += k1;
#define TFR(r) { x0 += x1; x1 = (x1 << (r)) | (x1 >> (32 - (r))); x1 ^= x0; }
  TFR(13) TFR(15) TFR(26) TFR(6)   x0 += k1;  x1 += ks2 + 1u;
  TFR(17) TFR(29) TFR(16) TFR(24)  x0 += ks2; x1 += k0 + 2u;
  TFR(13) TFR(15) TFR(26) TFR(6)   x0 += k0;  x1 += k1 + 3u;
  TFR(17) TFR(29) TFR(16) TFR(24)  x0 += k1;  x1 += ks2 + 4u;
  TFR(13) TFR(15) TFR(26) TFR(6)   x0 += ks2; x1 += k0 + 5u;
#undef TFR
  y0 = x0; y1 = x1;
}

__device__ inline uint32_t rb_bits(uint32_t k0, uint32_t k1, uint32_t idx) {
  uint32_t y0, y1;
  threefry2x32(k0, k1, 0u, idx, y0, y1);
  return y0 ^ y1;
}

__device__ inline double gumbel_from_bits(uint32_t bits) {
  uint32_t m = bits >> 9;
  float u = m ? (float)m * 1.1920928955078125e-07f : 1.17549435082228751e-38f;
  double lu = log((double)u);
  return -log(-lu);
}

__device__ inline uint16_t f2bf(float f) {
  union { float f; uint32_t u; } v; v.f = f;
  uint32_t u = v.u;
  return (uint16_t)((u + 0x7FFFu + ((u >> 16) & 1u)) >> 16);
}

__device__ inline double wredd(double v) {
#pragma unroll
  for (int o = 32; o > 0; o >>= 1) v += __shfl_xor(v, o, 64);
  return v;
}

// fast fp64 sincos for x in [0, ~4200): Cody-Waite 2-term pi/2 reduction
// + fdlibm minimax polys. abs error ~1e-16 — decisions bit-stable.
__device__ inline void fsincos(double x, double& sv, double& cv) {
  const double invpio2 = 6.36619772367581382433e-01;
  const double pio2_1  = 1.57079632673412561417e+00;
  const double pio2_1t = 6.07710050650619224932e-11;
  double fn = floor(x * invpio2 + 0.5);
  int n = (int)fn;
  double r = x - fn * pio2_1;
  r = r - fn * pio2_1t;
  double z = r * r;
  const double S1 = -1.66666666666666324348e-01, S2 = 8.33333333332248946124e-03,
               S3 = -1.98412698298579493134e-04, S4 = 2.75573137070700676789e-06,
               S5 = -2.50507602534068634195e-08, S6 = 1.58969099521155010221e-10;
  const double C1 = 4.16666666666666019037e-02, C2 = -1.38888888888741095749e-03,
               C3 = 2.48015872894767294178e-05, C4 = -2.75573143513906633035e-07,
               C5 = 2.08757232129817482790e-09, C6 = -1.13596475577881948265e-11;
  double ss = r + r * z * (S1 + z * (S2 + z * (S3 + z * (S4 + z * (S5 + z * S6)))));
  double cc = 1.0 + z * (-0.5 + z * (C1 + z * (C2 + z * (C3 + z * (C4 + z * (C5 + z * C6))))));
  int q = n & 3;
  sv = (q == 0) ? ss : (q == 1) ? cc : (q == 2) ? -ss : -cc;
  cv = (q == 0) ? cc : (q == 1) ? -ss : (q == 2) ? -cc : ss;
}

// ---- k_prep0: div table (256 fp64 exp) + PRNG keys ----
__global__ __launch_bounds__(64) void k_prep0(char* __restrict__ ws) {
  double* divt = (double*)(ws + WS_DIV);
  uint32_t* keys = (uint32_t*)(ws + WS_KEYS);
  int lane = threadIdx.x;
  const double c2 = -2.0 * 9.210340371976184 / 512.0;
  for (int it = 0; it < 4; ++it) {
    int f = it * 64 + lane;
    divt[f] = exp((double)f * c2);
  }
  if (lane < 2) {
    uint32_t y0, y1;
    threefry2x32(0u, 42u, 0u, (uint32_t)lane, y0, y1);
    keys[lane * 2] = y0; keys[lane * 2 + 1] = y1;
  }
}

// ---- k_prep: fp64 reduced operands + bf16 W^T (UNCHANGED from R4) ----
__global__ __launch_bounds__(64) void k_prep(
    const float* __restrict__ v0, const float* __restrict__ v1,
    const float* __restrict__ W, const float* __restrict__ be,
    const float* __restrict__ Wx, const float* __restrict__ Wv,
    char* __restrict__ ws) {
  double* Wex = (double*)(ws + WS_WEX);
  double* pex = (double*)(ws + WS_PEX);
  double* vWv = (double*)(ws + WS_VWV);
  const double* divt = (const double*)(ws + WS_DIV);
  uint16_t* Wt = (uint16_t*)(ws + WS_WT);
  int blk = blockIdx.x;
  int lane = threadIdx.x;

  if (blk < 512) {
    int d = blk;
    double a0 = 0.0, a1 = 0.0;
    for (int it = 0; it < 8; ++it) {
      int h = it * 64 + lane;
      double w = (double)W[d * 512 + h];
      a0 += w * (double)Wx[2 * h];
      a1 += w * (double)Wx[2 * h + 1];
    }
    a0 = wredd(a0); a1 = wredd(a1);
    if (lane == 0) { Wex[2 * d] = a0; Wex[2 * d + 1] = a1; }
  } else if (blk < 4608) {
    int t = blk - 512;
    double td = (double)t;
    double a0 = 0.0, a1 = 0.0;
    for (int it = 0; it < 8; ++it) {
      int h = it * 64 + lane;
      double dv = divt[h >> 1];
      double sv, cv;
      fsincos(td * dv, sv, cv);
      double pe = (h & 1) ? cv : sv;
      double pb = pe + (double)be[h];
      a0 += pb * (double)Wx[2 * h];
      a1 += pb * (double)Wx[2 * h + 1];
    }
    a0 = wredd(a0); a1 = wredd(a1);
    if (lane == 0) { pex[2 * t] = a0; pex[2 * t + 1] = a1; }
  } else if (blk < 4624) {
    int q = blk - 4608;
    int i = q >> 3, b = q & 7;
    const float* v = i ? v1 : v0;
    double a0 = 0.0, a1 = 0.0;
    for (int it = 0; it < 8; ++it) {
      int d = it * 64 + lane;
      double x = (double)v[b * 512 + d];
      a0 += x * (double)Wv[2 * d];
      a1 += x * (double)Wv[2 * d + 1];
    }
    a0 = wredd(a0); a1 = wredd(a1);
    if (lane == 0) { vWv[(i * 8 + b) * 2] = a0; vWv[(i * 8 + b) * 2 + 1] = a1; }
  } else {
    int kk = blk - 4624;
    for (int it = 0; it < 8; ++it) {
      int n = it * 64 + lane;
      Wt[(size_t)n * 512 + kk] = f2bf(W[kk * 512 + n]);
    }
  }
}

// ---- k_dot: one wave per token; fp64 dot only (HBM-bound) ----
__global__ __launch_bounds__(256) void k_dot(
    const float* __restrict__ data, const char* __restrict__ wsc,
    double* __restrict__ dd) {
  const double* Wex = (const double*)(wsc + WS_WEX);

  int k = blockIdx.x * 4 + (threadIdx.x >> 6);
  int lane = threadIdx.x & 63;

  const float4* dp = (const float4*)(data + (size_t)k * 512 + lane * 8);
  float4 f0 = dp[0], f1 = dp[1];
  float xv[8] = {f0.x, f0.y, f0.z, f0.w, f1.x, f1.y, f1.z, f1.w};
  const double* wx = Wex + lane * 16;
  double d0 = 0.0, d1 = 0.0;
#pragma unroll
  for (int u = 0; u < 8; ++u) {
    double x = (double)xv[u];
    d0 += x * wx[2 * u];
    d1 += x * wx[2 * u + 1];
  }
  d0 = wredd(d0); d1 = wredd(d1);
  if (lane == 0) { dd[2 * (size_t)k] = d0; dd[2 * (size_t)k + 1] = d1; }
}

// ---- k_scan: fused pick (gumbel argmax) + stable compaction scan ----
__global__ __launch_bounds__(1024) void k_scan(
    const double* __restrict__ dd, const float* __restrict__ bfp,
    const char* __restrict__ wsc, int* __restrict__ sel, int* __restrict__ lens) {
  const double* pex = (const double*)(wsc + WS_PEX);
  const double* vWv = (const double*)(wsc + WS_VWV);
  const uint32_t* keys = (const uint32_t*)(wsc + WS_KEYS);
  __shared__ int wsum[16];

  int b = blockIdx.x, tid = threadIdx.x;
  int wid = tid >> 6, lane = tid & 63;
  int t0 = tid * 4;
  double bf0 = (double)bfp[0], bf1 = (double)bfp[1];
  uint32_t k00 = keys[0], k01 = keys[1], k10 = keys[2], k11 = keys[3];
  double vA0 = vWv[(0 * 8 + b) * 2], vA1 = vWv[(0 * 8 + b) * 2 + 1];
  double vB0 = vWv[(1 * 8 + b) * 2], vB1 = vWv[(1 * 8 + b) * 2 + 1];

  int m[4], p = 0;
#pragma unroll
  for (int u = 0; u < 4; ++u) {
    int t = t0 + u;
    int k = b * 4096 + t;
    double d0 = dd[2 * (size_t)k], d1 = dd[2 * (size_t)k + 1];
    double l0 = 8.0 * (d0 + pex[t * 2]) + bf0;
    double l1 = 8.0 * (d1 + pex[t * 2 + 1]) + bf1;
    // filter 0
    double zA0 = l0 + vA0 + gumbel_from_bits(rb_bits(k00, k01, (uint32_t)(2 * k)));
    double zA1 = l1 + vA1 + gumbel_from_bits(rb_bits(k00, k01, (uint32_t)(2 * k + 1)));
    // filter 1
    double zB0 = l0 + vB0 + gumbel_from_bits(rb_bits(k10, k11, (uint32_t)(2 * k)));
    double zB1 = l1 + vB1 + gumbel_from_bits(rb_bits(k10, k11, (uint32_t)(2 * k + 1)));
    m[u] = ((zA0 >= zA1) && (zB0 >= zB1)) ? 1 : 0;
    p += m[u];
  }

  int s = p;
#pragma unroll
  for (int off = 1; off < 64; off <<= 1) {
    int v = __shfl_up(s, off, 64);
    if (lane >= off) s += v;
  }
  if (lane == 63) wsum[wid] = s;
  __syncthreads();
  if (wid == 0) {
    int w = (lane < 16) ? wsum[lane] : 0;
#pragma unroll
    for (int off = 1; off < 16; off <<= 1) {
      int v = __shfl_up(w, off, 64);
      if (lane >= off) w += v;
    }
    if (lane < 16) wsum[lane] = w;
  }
  __syncthreads();
  int woff = (wid > 0) ? wsum[wid - 1] : 0;
  int run = woff + s - p;
#pragma unroll
  for (int u = 0; u < 4; ++u) {
    if (m[u]) { sel[b * 4096 + run] = t0 + u; ++run; }
  }
  if (tid == 1023) lens[b] = wsum[15];
}

// ---- k_gather: pack selected rows -> bf16 Apack; zero-fill out rows j>=lens ----
__global__ __launch_bounds__(256) void k_gather(
    const float* __restrict__ data, const char* __restrict__ wsc,
    uint16_t* __restrict__ Apack, float* __restrict__ out) {
  const int* sel = (const int*)(wsc + WS_SEL);
  const int* lens = (const int*)(wsc + WS_LENS);
  int b = blockIdx.y;
  int j = blockIdx.x * 4 + (threadIdx.x >> 6);
  int lane = threadIdx.x & 63;
  int lensb = lens[b];
  if (j < lensb) {
    int t = sel[b * 4096 + j];
    const float* src = data + ((size_t)b * 4096 + t) * 512 + lane * 8;
    float4 a0 = *(const float4*)src;
    float4 a1 = *(const float4*)(src + 4);
    short8 o;
    o[0] = (short)f2bf(a0.x); o[1] = (short)f2bf(a0.y);
    o[2] = (short)f2bf(a0.z); o[3] = (short)f2bf(a0.w);
    o[4] = (short)f2bf(a1.x); o[5] = (short)f2bf(a1.y);
    o[6] = (short)f2bf(a1.z); o[7] = (short)f2bf(a1.w);
    *(short8*)(Apack + ((size_t)b * 4096 + j) * 512 + lane * 8) = o;
  } else {
    float4 z = {0.f, 0.f, 0.f, 0.f};
    float* op = out + ((size_t)(b * 4096 + j)) * 512 + lane * 8;
    *(float4*)op = z;
    *(float4*)(op + 4) = z;
  }
}

// ---- k_gemm v5: register double-buffered direct-from-global bf16 MFMA ----
// One wave per block (launch_bounds(64,1) -> full VGPR budget ~150 used:
// 64 acc + 2x32 frag ping-pong). Loads for iter k+1 are all in flight while
// iter k's 16 MFMAs issue -> compiler emits s_waitcnt vmcnt(8), never 0
// (the AITER pattern). Grid nb-fastest: consecutive blocks share the A tile.
__global__ __launch_bounds__(64, 1) void k_gemm(
    const uint16_t* __restrict__ Apack, const float* __restrict__ be,
    const char* __restrict__ wsc, float* __restrict__ out) {
  const uint16_t* Wt = (const uint16_t*)(wsc + WS_WT);
  const int* sel = (const int*)(wsc + WS_SEL);
  const int* lens = (const int*)(wsc + WS_LENS);

  int nb = blockIdx.x;   // 0..7   64-col stripe
  int mb = blockIdx.y;   // 0..63  64-row stripe
  int b = blockIdx.z;
  int lane = threadIdx.x;
  int lensb = lens[b];
  int jbase = mb * 64;
  if (jbase >= lensb) return;   // rows zeroed by k_gather

  int quad = lane >> 4, l15 = lane & 15;

  f32x4 acc[4][4] = {};
  const uint16_t* aBase = Apack + ((size_t)b * 4096 + jbase) * 512 + quad * 8;
  const uint16_t* bBase = Wt + ((size_t)(nb * 64)) * 512 + quad * 8;

  short8 af[2][4], bfr[2][4];
#pragma unroll
  for (int mi = 0; mi < 4; ++mi)
    af[0][mi] = *(const short8*)(aBase + (size_t)(mi * 16 + l15) * 512);
#pragma unroll
  for (int ni = 0; ni < 4; ++ni)
    bfr[0][ni] = *(const short8*)(bBase + (size_t)(ni * 16 + l15) * 512);

#pragma unroll
  for (int it = 0; it < 16; ++it) {
    int cur = it & 1, nxt = cur ^ 1;
    if (it < 15) {
      int k1 = (it + 1) * 32;
#pragma unroll
      for (int mi = 0; mi < 4; ++mi)
        af[nxt][mi] = *(const short8*)(aBase + (size_t)(mi * 16 + l15) * 512 + k1);
#pragma unroll
      for (int ni = 0; ni < 4; ++ni)
        bfr[nxt][ni] = *(const short8*)(bBase + (size_t)(ni * 16 + l15) * 512 + k1);
    }
#pragma unroll
    for (int mi = 0; mi < 4; ++mi)
#pragma unroll
      for (int ni = 0; ni < 4; ++ni)
        acc[mi][ni] = __builtin_amdgcn_mfma_f32_16x16x32_bf16(af[cur][mi], bfr[cur][ni], acc[mi][ni], 0, 0, 0);
  }

  // fused epilogue: out = 8*(acc + be[n] + pe(t,n)) only for valid rows
  const float c1 = -0.01798894603951557739f;  // -ln(10000)/512
#pragma unroll
  for (int ni = 0; ni < 4; ++ni) {
    int n = nb * 64 + ni * 16 + l15;
    float dv = __expf((float)(n & ~1) * c1);
    float ben = be[n];
#pragma unroll
    for (int mi = 0; mi < 4; ++mi) {
#pragma unroll
      for (int r = 0; r < 4; ++r) {
        int j = jbase + mi * 16 + quad * 4 + r;
        if (j < lensb) {
          int t = sel[b * 4096 + j];
          float ph = (float)t * dv;
          float pe = (n & 1) ? __cosf(ph) : __sinf(ph);
          out[((size_t)(b * 4096 + j)) * 512 + n] = 8.0f * (acc[mi][ni][r] + ben + pe);
        }
      }
    }
  }
}

extern "C" void kernel_launch(void* const* d_in, const int* in_sizes, int n_in,
                              void* d_out, int out_size, void* d_ws, size_t ws_size,
                              hipStream_t stream) {
  const float* data = (const float*)d_in[0];
  const float* v0   = (const float*)d_in[1];
  const float* v1   = (const float*)d_in[2];
  const float* W    = (const float*)d_in[3];
  const float* be   = (const float*)d_in[4];
  const float* Wx   = (const float*)d_in[5];
  const float* Wv   = (const float*)d_in[6];
  const float* bfp  = (const float*)d_in[7];
  char* ws = (char*)d_ws;
  float* out = (float*)d_out;
  uint16_t* Apack = (uint16_t*)(ws + WS_APACK);
  double* dd = (double*)(ws + WS_DD);

  hipLaunchKernelGGL(k_prep0, dim3(1), dim3(64), 0, stream, ws);
  hipLaunchKernelGGL(k_prep, dim3(5136), dim3(64), 0, stream, v0, v1, W, be, Wx, Wv, ws);
  hipLaunchKernelGGL(k_dot, dim3(8192), dim3(256), 0, stream, data, (const char*)ws, dd);
  hipLaunchKernelGGL(k_scan, dim3(8), dim3(1024), 0, stream,
                     (const double*)dd, bfp, (const char*)ws,
                     (int*)(ws + WS_SEL), (int*)(ws + WS_LENS));
  hipLaunchKernelGGL(k_gather, dim3(1024, 8), dim3(256), 0, stream,
                     data, (const char*)ws, Apack, out);
  hipLaunchKernelGGL(k_gemm, dim3(8, 64, 8), dim3(64), 0, stream,
                     Apack, be, (const char*)ws, out);
}

// Round 6
// 225.337 us; speedup vs baseline: 1.0660x; 1.0660x over previous
//
#include <hip/hip_runtime.h>
#include <stdint.h>

// PRNG layout: partitionable counter-mode, bits = y0 ^ y1 (verified round 1)

#define NB 8
#define NT 4096
#define ND 512
#define NH 512
#define NTOK (NB * NT)

typedef __attribute__((ext_vector_type(8))) short short8;
typedef __attribute__((ext_vector_type(4))) float f32x4;

// ---- workspace layout (bytes) ----
#define WS_WEX   0          // 512*2 f64   : W_embed @ Wx
#define WS_PEX   8192       // 4096*2 f64  : (b_embed + pe[t]) @ Wx
#define WS_VWV   73728      // 2*8*2 f64   : v_i @ Wv
#define WS_KEYS  73984      // 4 u32       : fold_in keys
#define WS_DIV   74000      // 256 f64     : div table
#define WS_LENS  76048      // 8 i32
#define WS_WT    76096      // 512*512 u16 : bf16 W_embed transposed [n][k]
#define WS_INV   600384     // 32768 i32   : token -> packed pos (-1 dropped)
#define WS_DD    731456     // 32768*2 f64 : dot results
#define WS_ABF16 1310720    // 32768*512 u16 : dense bf16 data

__device__ inline void threefry2x32(uint32_t k0, uint32_t k1, uint32_t x0, uint32_t x1,
                                    uint32_t& y0, uint32_t& y1) {
  uint32_t ks2 = k0 ^ k1 ^ 0x1BD11BDAu;
  x0 += k0; x1 += k1;
#define TFR(r) { x0 += x1; x1 = (x1 << (r)) | (x1 >> (32 - (r))); x1 ^= x0; }
  TFR(13) TFR(15) TFR(26) TFR(6)   x0 += k1;  x1 += ks2 + 1u;
  TFR(17) TFR(29) TFR(16) TFR(24)  x0 += ks2; x1 += k0 + 2u;
  TFR(13) TFR(15) TFR(26) TFR(6)   x0 += k0;  x1 += k1 + 3u;
  TFR(17) TFR(29) TFR(16) TFR(24)  x0 += k1;  x1 += ks2 + 4u;
  TFR(13) TFR(15) TFR(26) TFR(6)   x0 += ks2; x1 += k0 + 5u;
#undef TFR
  y0 = x0; y1 = x1;
}

__device__ inline uint32_t rb_bits(uint32_t k0, uint32_t k1, uint32_t idx) {
  uint32_t y0, y1;
  threefry2x32(k0, k1, 0u, idx, y0, y1);
  return y0 ^ y1;
}

__device__ inline double gumbel_from_bits(uint32_t bits) {
  uint32_t m = bits >> 9;
  float u = m ? (float)m * 1.1920928955078125e-07f : 1.17549435082228751e-38f;
  double lu = log((double)u);
  return -log(-lu);
}

__device__ inline uint16_t f2bf(float f) {
  union { float f; uint32_t u; } v; v.f = f;
  uint32_t u = v.u;
  return (uint16_t)((u + 0x7FFFu + ((u >> 16) & 1u)) >> 16);
}

__device__ inline double wredd(double v) {
#pragma unroll
  for (int o = 32; o > 0; o >>= 1) v += __shfl_xor(v, o, 64);
  return v;
}

// fast fp64 sincos for x in [0, ~4200): Cody-Waite + fdlibm polys, err ~1e-16
__device__ inline void fsincos(double x, double& sv, double& cv) {
  const double invpio2 = 6.36619772367581382433e-01;
  const double pio2_1  = 1.57079632673412561417e+00;
  const double pio2_1t = 6.07710050650619224932e-11;
  double fn = floor(x * invpio2 + 0.5);
  int n = (int)fn;
  double r = x - fn * pio2_1;
  r = r - fn * pio2_1t;
  double z = r * r;
  const double S1 = -1.66666666666666324348e-01, S2 = 8.33333333332248946124e-03,
               S3 = -1.98412698298579493134e-04, S4 = 2.75573137070700676789e-06,
               S5 = -2.50507602534068634195e-08, S6 = 1.58969099521155010221e-10;
  const double C1 = 4.16666666666666019037e-02, C2 = -1.38888888888741095749e-03,
               C3 = 2.48015872894767294178e-05, C4 = -2.75573143513906633035e-07,
               C5 = 2.08757232129817482790e-09, C6 = -1.13596475577881948265e-11;
  double ss = r + r * z * (S1 + z * (S2 + z * (S3 + z * (S4 + z * (S5 + z * S6)))));
  double cc = 1.0 + z * (-0.5 + z * (C1 + z * (C2 + z * (C3 + z * (C4 + z * (C5 + z * C6))))));
  int q = n & 3;
  sv = (q == 0) ? ss : (q == 1) ? cc : (q == 2) ? -ss : -cc;
  cv = (q == 0) ? cc : (q == 1) ? -ss : (q == 2) ? -cc : ss;
}

__device__ inline void gld_lds16(const void* g, void* l) {
  __builtin_amdgcn_global_load_lds(
      (const __attribute__((address_space(1))) void*)g,
      (__attribute__((address_space(3))) void*)l, 16, 0, 0);
}

// ---- k_prep0: div table + PRNG keys ----
__global__ __launch_bounds__(64) void k_prep0(char* __restrict__ ws) {
  double* divt = (double*)(ws + WS_DIV);
  uint32_t* keys = (uint32_t*)(ws + WS_KEYS);
  int lane = threadIdx.x;
  const double c2 = -2.0 * 9.210340371976184 / 512.0;
  for (int it = 0; it < 4; ++it) {
    int f = it * 64 + lane;
    divt[f] = exp((double)f * c2);
  }
  if (lane < 2) {
    uint32_t y0, y1;
    threefry2x32(0u, 42u, 0u, (uint32_t)lane, y0, y1);
    keys[lane * 2] = y0; keys[lane * 2 + 1] = y1;
  }
}

// ---- k_prep: fp64 reduced operands + bf16 W^T (decision math UNCHANGED) ----
__global__ __launch_bounds__(64) void k_prep(
    const float* __restrict__ v0, const float* __restrict__ v1,
    const float* __restrict__ W, const float* __restrict__ be,
    const float* __restrict__ Wx, const float* __restrict__ Wv,
    char* __restrict__ ws) {
  double* Wex = (double*)(ws + WS_WEX);
  double* pex = (double*)(ws + WS_PEX);
  double* vWv = (double*)(ws + WS_VWV);
  const double* divt = (const double*)(ws + WS_DIV);
  uint16_t* Wt = (uint16_t*)(ws + WS_WT);
  int blk = blockIdx.x;
  int lane = threadIdx.x;

  if (blk < 512) {
    int d = blk;
    double a0 = 0.0, a1 = 0.0;
    for (int it = 0; it < 8; ++it) {
      int h = it * 64 + lane;
      double w = (double)W[d * 512 + h];
      a0 += w * (double)Wx[2 * h];
      a1 += w * (double)Wx[2 * h + 1];
    }
    a0 = wredd(a0); a1 = wredd(a1);
    if (lane == 0) { Wex[2 * d] = a0; Wex[2 * d + 1] = a1; }
  } else if (blk < 4608) {
    int t = blk - 512;
    double td = (double)t;
    double a0 = 0.0, a1 = 0.0;
    for (int it = 0; it < 8; ++it) {
      int h = it * 64 + lane;
      double dv = divt[h >> 1];
      double sv, cv;
      fsincos(td * dv, sv, cv);
      double pe = (h & 1) ? cv : sv;
      double pb = pe + (double)be[h];
      a0 += pb * (double)Wx[2 * h];
      a1 += pb * (double)Wx[2 * h + 1];
    }
    a0 = wredd(a0); a1 = wredd(a1);
    if (lane == 0) { pex[2 * t] = a0; pex[2 * t + 1] = a1; }
  } else if (blk < 4624) {
    int q = blk - 4608;
    int i = q >> 3, b = q & 7;
    const float* v = i ? v1 : v0;
    double a0 = 0.0, a1 = 0.0;
    for (int it = 0; it < 8; ++it) {
      int d = it * 64 + lane;
      double x = (double)v[b * 512 + d];
      a0 += x * (double)Wv[2 * d];
      a1 += x * (double)Wv[2 * d + 1];
    }
    a0 = wredd(a0); a1 = wredd(a1);
    if (lane == 0) { vWv[(i * 8 + b) * 2] = a0; vWv[(i * 8 + b) * 2 + 1] = a1; }
  } else {
    int kk = blk - 4624;
    for (int it = 0; it < 8; ++it) {
      int n = it * 64 + lane;
      Wt[(size_t)n * 512 + kk] = f2bf(W[kk * 512 + n]);
    }
  }
}

// ---- k_dot: fp64 dot per token + dense bf16 conversion of data ----
__global__ __launch_bounds__(256) void k_dot(
    const float* __restrict__ data, const char* __restrict__ wsc,
    double* __restrict__ dd, uint16_t* __restrict__ Abf) {
  const double* Wex = (const double*)(wsc + WS_WEX);

  int k = blockIdx.x * 4 + (threadIdx.x >> 6);
  int lane = threadIdx.x & 63;

  const float4* dp = (const float4*)(data + (size_t)k * 512 + lane * 8);
  float4 f0 = dp[0], f1 = dp[1];
  float xv[8] = {f0.x, f0.y, f0.z, f0.w, f1.x, f1.y, f1.z, f1.w};

  // dense bf16 side-write (feeds k_gemm)
  short8 o;
#pragma unroll
  for (int u = 0; u < 8; ++u) o[u] = (short)f2bf(xv[u]);
  *(short8*)(Abf + (size_t)k * 512 + lane * 8) = o;

  const double* wx = Wex + lane * 16;
  double d0 = 0.0, d1 = 0.0;
#pragma unroll
  for (int u = 0; u < 8; ++u) {
    double x = (double)xv[u];
    d0 += x * wx[2 * u];
    d1 += x * wx[2 * u + 1];
  }
  d0 = wredd(d0); d1 = wredd(d1);
  if (lane == 0) { dd[2 * (size_t)k] = d0; dd[2 * (size_t)k + 1] = d1; }
}

// ---- k_scan: fused gumbel argmax + stable compaction -> inv map + lens ----
__global__ __launch_bounds__(1024) void k_scan(
    const double* __restrict__ dd, const float* __restrict__ bfp,
    const char* __restrict__ wsc, int* __restrict__ inv, int* __restrict__ lens) {
  const double* pex = (const double*)(wsc + WS_PEX);
  const double* vWv = (const double*)(wsc + WS_VWV);
  const uint32_t* keys = (const uint32_t*)(wsc + WS_KEYS);
  __shared__ int wsum[16];

  int b = blockIdx.x, tid = threadIdx.x;
  int wid = tid >> 6, lane = tid & 63;
  int t0 = tid * 4;
  double bf0 = (double)bfp[0], bf1 = (double)bfp[1];
  uint32_t k00 = keys[0], k01 = keys[1], k10 = keys[2], k11 = keys[3];
  double vA0 = vWv[(0 * 8 + b) * 2], vA1 = vWv[(0 * 8 + b) * 2 + 1];
  double vB0 = vWv[(1 * 8 + b) * 2], vB1 = vWv[(1 * 8 + b) * 2 + 1];

  int m[4], p = 0;
#pragma unroll
  for (int u = 0; u < 4; ++u) {
    int t = t0 + u;
    int k = b * 4096 + t;
    double d0 = dd[2 * (size_t)k], d1 = dd[2 * (size_t)k + 1];
    double l0 = 8.0 * (d0 + pex[t * 2]) + bf0;
    double l1 = 8.0 * (d1 + pex[t * 2 + 1]) + bf1;
    double zA0 = l0 + vA0 + gumbel_from_bits(rb_bits(k00, k01, (uint32_t)(2 * k)));
    double zA1 = l1 + vA1 + gumbel_from_bits(rb_bits(k00, k01, (uint32_t)(2 * k + 1)));
    double zB0 = l0 + vB0 + gumbel_from_bits(rb_bits(k10, k11, (uint32_t)(2 * k)));
    double zB1 = l1 + vB1 + gumbel_from_bits(rb_bits(k10, k11, (uint32_t)(2 * k + 1)));
    m[u] = ((zA0 >= zA1) && (zB0 >= zB1)) ? 1 : 0;
    p += m[u];
  }

  int s = p;
#pragma unroll
  for (int off = 1; off < 64; off <<= 1) {
    int v = __shfl_up(s, off, 64);
    if (lane >= off) s += v;
  }
  if (lane == 63) wsum[wid] = s;
  __syncthreads();
  if (wid == 0) {
    int w = (lane < 16) ? wsum[lane] : 0;
#pragma unroll
    for (int off = 1; off < 16; off <<= 1) {
      int v = __shfl_up(w, off, 64);
      if (lane >= off) w += v;
    }
    if (lane < 16) wsum[lane] = w;
  }
  __syncthreads();
  int run = ((wid > 0) ? wsum[wid - 1] : 0) + s - p;
  int4 iv;
  iv.x = m[0] ? run : -1; run += m[0];
  iv.y = m[1] ? run : -1; run += m[1];
  iv.z = m[2] ? run : -1; run += m[2];
  iv.w = m[3] ? run : -1;
  *(int4*)(inv + b * 4096 + t0) = iv;
  if (tid == 1023) lens[b] = wsum[15];
}

// ---- k_zero: fill out rows j >= lens[b] with zeros ----
__global__ __launch_bounds__(256) void k_zero(
    const char* __restrict__ wsc, float* __restrict__ out) {
  const int* lens = (const int*)(wsc + WS_LENS);
  int b = blockIdx.y;
  int j = blockIdx.x * 4 + (threadIdx.x >> 6);
  if (j < lens[b]) return;
  int lane = threadIdx.x & 63;
  float4 z = {0.f, 0.f, 0.f, 0.f};
  float* op = out + ((size_t)(b * 4096 + j)) * 512 + lane * 8;
  *(float4*)op = z;
  *(float4*)(op + 4) = z;
}

// ---- k_gemm v6: DENSE m97-style LDS-staged bf16 MFMA + scatter epilogue ----
// All 32768 rows computed (17.2 GFLOP): 1024 blocks x 4 waves = full occupancy;
// epilogue scatters selected rows via inv[], dropped rows write nothing.
#define BM 128
#define BN 128
#define BK 32

__global__ __launch_bounds__(256) void k_gemm(
    const uint16_t* __restrict__ Abf, const float* __restrict__ be,
    const char* __restrict__ wsc, float* __restrict__ out) {
  const uint16_t* Wt = (const uint16_t*)(wsc + WS_WT);
  const int* inv = (const int*)(wsc + WS_INV);

  int g0 = blockIdx.x * BM;       // global row base (8*4096 rows total)
  int nb = blockIdx.y;
  int b = g0 >> 12;
  int tid = threadIdx.x;
  int wave = tid >> 6, lane = tid & 63;
  int wm = wave & 1, wn = wave >> 1;
  int quad = lane >> 4, l15 = lane & 15;
  int srow = lane >> 2;
  int scol = (lane & 3) * 8;

  __shared__ __align__(16) uint16_t As[BM * BK];
  __shared__ __align__(16) uint16_t Bs[BN * BK];

  f32x4 acc[4][4] = {};

  const uint16_t* gA = Abf + (size_t)g0 * 512;
  const uint16_t* gB = Wt + (size_t)(nb * BN) * 512;
  uint16_t* lA = As + (size_t)(wave * 16) * BK;  // wave-uniform LDS base
  uint16_t* lB = Bs + (size_t)(wave * 16) * BK;

  for (int k0 = 0; k0 < 512; k0 += BK) {
    gld_lds16(gA + (size_t)(wave * 16 + srow) * 512 + k0 + scol, lA);
    gld_lds16(gA + (size_t)(64 + wave * 16 + srow) * 512 + k0 + scol, lA + 64 * BK);
    gld_lds16(gB + (size_t)(wave * 16 + srow) * 512 + k0 + scol, lB);
    gld_lds16(gB + (size_t)(64 + wave * 16 + srow) * 512 + k0 + scol, lB + 64 * BK);
    __syncthreads();

    short8 af[4], bfr[4];
#pragma unroll
    for (int mi = 0; mi < 4; ++mi)
      af[mi] = *(const short8*)&As[(wm * 64 + mi * 16 + l15) * BK + quad * 8];
#pragma unroll
    for (int ni = 0; ni < 4; ++ni)
      bfr[ni] = *(const short8*)&Bs[(wn * 64 + ni * 16 + l15) * BK + quad * 8];
#pragma unroll
    for (int mi = 0; mi < 4; ++mi)
#pragma unroll
      for (int ni = 0; ni < 4; ++ni)
        acc[mi][ni] = __builtin_amdgcn_mfma_f32_16x16x32_bf16(af[mi], bfr[ni], acc[mi][ni], 0, 0, 0);
    __syncthreads();
  }

  // preload this block's 128 inv entries into LDS (As is dead now)
  int* invs = (int*)As;
  if (tid < 128) invs[tid] = inv[g0 + tid];
  __syncthreads();

  // scatter epilogue: selected rows -> out[b][pj][:], 8*(acc + be + pe(t,n))
  const float c1 = -0.01798894603951557739f;  // -ln(10000)/512
#pragma unroll
  for (int ni = 0; ni < 4; ++ni) {
    int n = nb * BN + wn * 64 + ni * 16 + l15;
    float dv = __expf((float)(n & ~1) * c1);
    float ben = be[n];
#pragma unroll
    for (int mi = 0; mi < 4; ++mi) {
#pragma unroll
      for (int r = 0; r < 4; ++r) {
        int lrow = wm * 64 + mi * 16 + quad * 4 + r;
        int pj = invs[lrow];
        if (pj >= 0) {
          int t = (g0 + lrow) & 4095;
          float ph = (float)t * dv;
          float pe = (n & 1) ? __cosf(ph) : __sinf(ph);
          out[((size_t)(b * 4096 + pj)) * 512 + n] = 8.0f * (acc[mi][ni][r] + ben + pe);
        }
      }
    }
  }
}

extern "C" void kernel_launch(void* const* d_in, const int* in_sizes, int n_in,
                              void* d_out, int out_size, void* d_ws, size_t ws_size,
                              hipStream_t stream) {
  const float* data = (const float*)d_in[0];
  const float* v0   = (const float*)d_in[1];
  const float* v1   = (const float*)d_in[2];
  const float* W    = (const float*)d_in[3];
  const float* be   = (const float*)d_in[4];
  const float* Wx   = (const float*)d_in[5];
  const float* Wv   = (const float*)d_in[6];
  const float* bfp  = (const float*)d_in[7];
  char* ws = (char*)d_ws;
  float* out = (float*)d_out;
  uint16_t* Abf = (uint16_t*)(ws + WS_ABF16);
  double* dd = (double*)(ws + WS_DD);

  hipLaunchKernelGGL(k_prep0, dim3(1), dim3(64), 0, stream, ws);
  hipLaunchKernelGGL(k_prep, dim3(5136), dim3(64), 0, stream, v0, v1, W, be, Wx, Wv, ws);
  hipLaunchKernelGGL(k_dot, dim3(8192), dim3(256), 0, stream, data, (const char*)ws, dd, Abf);
  hipLaunchKernelGGL(k_scan, dim3(8), dim3(1024), 0, stream,
                     (const double*)dd, bfp, (const char*)ws,
                     (int*)(ws + WS_INV), (int*)(ws + WS_LENS));
  hipLaunchKernelGGL(k_zero, dim3(1024, 8), dim3(256), 0, stream, (const char*)ws, out);
  hipLaunchKernelGGL(k_gemm, dim3(256, 4), dim3(256), 0, stream,
                     Abf, be, (const char*)ws, out);
}

// Round 7
// 205.764 us; speedup vs baseline: 1.1674x; 1.0951x over previous
//
#include <hip/hip_runtime.h>
#include <stdint.h>

// PRNG layout: partitionable counter-mode, bits = y0 ^ y1 (verified round 1)

#define NB 8
#define NT 4096
#define ND 512
#define NH 512
#define NTOK (NB * NT)

typedef __attribute__((ext_vector_type(8))) short short8;
typedef __attribute__((ext_vector_type(4))) float f32x4;

// ---- workspace layout (bytes) ----
#define WS_WEX   0          // 512*2 f64   : W_embed @ Wx
#define WS_PEX   8192       // 4096*2 f64  : (b_embed + pe[t]) @ Wx
#define WS_VWV   73728      // 2*8*2 f64   : v_i @ Wv
#define WS_KEYS  73984      // 4 u32       : fold_in keys
#define WS_DIV   74000      // 256 f64     : div table
#define WS_LENS  76048      // 8 i32
#define WS_WT    76096      // 512*512 u16 : bf16 W_embed transposed [n][k]
#define WS_INV   600384     // 32768 i32   : token -> packed pos (-1 dropped)
#define WS_MASK  731456     // 32768 i32   : keep mask
#define WS_ABF16 1310720    // 32768*512 u16 : dense bf16 data

__device__ inline void threefry2x32(uint32_t k0, uint32_t k1, uint32_t x0, uint32_t x1,
                                    uint32_t& y0, uint32_t& y1) {
  uint32_t ks2 = k0 ^ k1 ^ 0x1BD11BDAu;
  x0 += k0; x1 += k1;
#define TFR(r) { x0 += x1; x1 = (x1 << (r)) | (x1 >> (32 - (r))); x1 ^= x0; }
  TFR(13) TFR(15) TFR(26) TFR(6)   x0 += k1;  x1 += ks2 + 1u;
  TFR(17) TFR(29) TFR(16) TFR(24)  x0 += ks2; x1 += k0 + 2u;
  TFR(13) TFR(15) TFR(26) TFR(6)   x0 += k0;  x1 += k1 + 3u;
  TFR(17) TFR(29) TFR(16) TFR(24)  x0 += k1;  x1 += ks2 + 4u;
  TFR(13) TFR(15) TFR(26) TFR(6)   x0 += ks2; x1 += k0 + 5u;
#undef TFR
  y0 = x0; y1 = x1;
}

__device__ inline uint32_t rb_bits(uint32_t k0, uint32_t k1, uint32_t idx) {
  uint32_t y0, y1;
  threefry2x32(k0, k1, 0u, idx, y0, y1);
  return y0 ^ y1;
}

__device__ inline double gumbel_from_bits(uint32_t bits) {
  uint32_t m = bits >> 9;
  float u = m ? (float)m * 1.1920928955078125e-07f : 1.17549435082228751e-38f;
  double lu = log((double)u);
  return -log(-lu);
}

__device__ inline uint16_t f2bf(float f) {
  union { float f; uint32_t u; } v; v.f = f;
  uint32_t u = v.u;
  return (uint16_t)((u + 0x7FFFu + ((u >> 16) & 1u)) >> 16);
}

__device__ inline double wredd(double v) {
#pragma unroll
  for (int o = 32; o > 0; o >>= 1) v += __shfl_xor(v, o, 64);
  return v;
}

// fast fp64 sincos for x in [0, ~4200): Cody-Waite + fdlibm polys, err ~1e-16
__device__ inline void fsincos(double x, double& sv, double& cv) {
  const double invpio2 = 6.36619772367581382433e-01;
  const double pio2_1  = 1.57079632673412561417e+00;
  const double pio2_1t = 6.07710050650619224932e-11;
  double fn = floor(x * invpio2 + 0.5);
  int n = (int)fn;
  double r = x - fn * pio2_1;
  r = r - fn * pio2_1t;
  double z = r * r;
  const double S1 = -1.66666666666666324348e-01, S2 = 8.33333333332248946124e-03,
               S3 = -1.98412698298579493134e-04, S4 = 2.75573137070700676789e-06,
               S5 = -2.50507602534068634195e-08, S6 = 1.58969099521155010221e-10;
  const double C1 = 4.16666666666666019037e-02, C2 = -1.38888888888741095749e-03,
               C3 = 2.48015872894767294178e-05, C4 = -2.75573143513906633035e-07,
               C5 = 2.08757232129817482790e-09, C6 = -1.13596475577881948265e-11;
  double ss = r + r * z * (S1 + z * (S2 + z * (S3 + z * (S4 + z * (S5 + z * S6)))));
  double cc = 1.0 + z * (-0.5 + z * (C1 + z * (C2 + z * (C3 + z * (C4 + z * (C5 + z * C6))))));
  int q = n & 3;
  sv = (q == 0) ? ss : (q == 1) ? cc : (q == 2) ? -ss : -cc;
  cv = (q == 0) ? cc : (q == 1) ? -ss : (q == 2) ? -cc : ss;
}

__device__ inline void gld_lds16(const void* g, void* l) {
  __builtin_amdgcn_global_load_lds(
      (const __attribute__((address_space(1))) void*)g,
      (__attribute__((address_space(3))) void*)l, 16, 0, 0);
}

// ---- k_prep0: div table + PRNG keys ----
__global__ __launch_bounds__(64) void k_prep0(char* __restrict__ ws) {
  double* divt = (double*)(ws + WS_DIV);
  uint32_t* keys = (uint32_t*)(ws + WS_KEYS);
  int lane = threadIdx.x;
  const double c2 = -2.0 * 9.210340371976184 / 512.0;
  for (int it = 0; it < 4; ++it) {
    int f = it * 64 + lane;
    divt[f] = exp((double)f * c2);
  }
  if (lane < 2) {
    uint32_t y0, y1;
    threefry2x32(0u, 42u, 0u, (uint32_t)lane, y0, y1);
    keys[lane * 2] = y0; keys[lane * 2 + 1] = y1;
  }
}

// ---- k_prep: fp64 reduced operands + bf16 W^T (decision math UNCHANGED) ----
__global__ __launch_bounds__(64) void k_prep(
    const float* __restrict__ v0, const float* __restrict__ v1,
    const float* __restrict__ W, const float* __restrict__ be,
    const float* __restrict__ Wx, const float* __restrict__ Wv,
    char* __restrict__ ws) {
  double* Wex = (double*)(ws + WS_WEX);
  double* pex = (double*)(ws + WS_PEX);
  double* vWv = (double*)(ws + WS_VWV);
  const double* divt = (const double*)(ws + WS_DIV);
  uint16_t* Wt = (uint16_t*)(ws + WS_WT);
  int blk = blockIdx.x;
  int lane = threadIdx.x;

  if (blk < 512) {
    int d = blk;
    double a0 = 0.0, a1 = 0.0;
    for (int it = 0; it < 8; ++it) {
      int h = it * 64 + lane;
      double w = (double)W[d * 512 + h];
      a0 += w * (double)Wx[2 * h];
      a1 += w * (double)Wx[2 * h + 1];
    }
    a0 = wredd(a0); a1 = wredd(a1);
    if (lane == 0) { Wex[2 * d] = a0; Wex[2 * d + 1] = a1; }
  } else if (blk < 4608) {
    int t = blk - 512;
    double td = (double)t;
    double a0 = 0.0, a1 = 0.0;
    for (int it = 0; it < 8; ++it) {
      int h = it * 64 + lane;
      double dv = divt[h >> 1];
      double sv, cv;
      fsincos(td * dv, sv, cv);
      double pe = (h & 1) ? cv : sv;
      double pb = pe + (double)be[h];
      a0 += pb * (double)Wx[2 * h];
      a1 += pb * (double)Wx[2 * h + 1];
    }
    a0 = wredd(a0); a1 = wredd(a1);
    if (lane == 0) { pex[2 * t] = a0; pex[2 * t + 1] = a1; }
  } else if (blk < 4624) {
    int q = blk - 4608;
    int i = q >> 3, b = q & 7;
    const float* v = i ? v1 : v0;
    double a0 = 0.0, a1 = 0.0;
    for (int it = 0; it < 8; ++it) {
      int d = it * 64 + lane;
      double x = (double)v[b * 512 + d];
      a0 += x * (double)Wv[2 * d];
      a1 += x * (double)Wv[2 * d + 1];
    }
    a0 = wredd(a0); a1 = wredd(a1);
    if (lane == 0) { vWv[(i * 8 + b) * 2] = a0; vWv[(i * 8 + b) * 2 + 1] = a1; }
  } else {
    int kk = blk - 4624;
    for (int it = 0; it < 8; ++it) {
      int n = it * 64 + lane;
      Wt[(size_t)n * 512 + kk] = f2bf(W[kk * 512 + n]);
    }
  }
}

// ---- k_dot: fp64 dot + bf16 conversion + fused gumbel decision -> mask ----
__global__ __launch_bounds__(256) void k_dot(
    const float* __restrict__ data, const float* __restrict__ bfp,
    const char* __restrict__ wsc, int* __restrict__ mask,
    uint16_t* __restrict__ Abf) {
  const double* Wex = (const double*)(wsc + WS_WEX);
  const double* pex = (const double*)(wsc + WS_PEX);
  const double* vWv = (const double*)(wsc + WS_VWV);
  const uint32_t* keys = (const uint32_t*)(wsc + WS_KEYS);

  int k = blockIdx.x * 4 + (threadIdx.x >> 6);
  int lane = threadIdx.x & 63;
  int b = k >> 12, t = k & 4095;

  const float4* dp = (const float4*)(data + (size_t)k * 512 + lane * 8);
  float4 f0 = dp[0], f1 = dp[1];
  float xv[8] = {f0.x, f0.y, f0.z, f0.w, f1.x, f1.y, f1.z, f1.w};

  // dense bf16 side-write (feeds k_gemm)
  short8 o;
#pragma unroll
  for (int u = 0; u < 8; ++u) o[u] = (short)f2bf(xv[u]);
  *(short8*)(Abf + (size_t)k * 512 + lane * 8) = o;

  const double* wx = Wex + lane * 16;
  double d0 = 0.0, d1 = 0.0;
#pragma unroll
  for (int u = 0; u < 8; ++u) {
    double x = (double)xv[u];
    d0 += x * wx[2 * u];
    d1 += x * wx[2 * u + 1];
  }
  d0 = wredd(d0); d1 = wredd(d1);

  // decision on lanes 0-3: lane = 2*filter + class
  int dec = 0;
  if (lane < 4) {
    int i = lane >> 1, j = lane & 1;
    double lj = 8.0 * ((j ? d1 : d0) + pex[t * 2 + j]) + (double)bfp[j];
    double z = lj + vWv[(i * 8 + b) * 2 + j]
                 + gumbel_from_bits(rb_bits(keys[i * 2], keys[i * 2 + 1],
                                            (uint32_t)(2 * k + j)));
    double zo = __shfl_xor(z, 1, 64);
    dec = (z >= zo) ? 1 : 0;  // meaningful on lanes 0 (f0) and 2 (f1)
  }
  int dA = __shfl(dec, 0, 64);
  int dB = __shfl(dec, 2, 64);
  if (lane == 0) mask[k] = dA & dB;
}

// ---- k_scan: pure mask -> inv prefix scan + lens (light) ----
__global__ __launch_bounds__(1024) void k_scan(
    const int* __restrict__ mask, int* __restrict__ inv, int* __restrict__ lens) {
  __shared__ int wsum[16];
  int b = blockIdx.x, tid = threadIdx.x;
  int wid = tid >> 6, lane = tid & 63;
  int t0 = tid * 4;
  int4 mv = *(const int4*)(mask + b * 4096 + t0);
  int m[4] = {mv.x, mv.y, mv.z, mv.w};
  int p = m[0] + m[1] + m[2] + m[3];

  int s = p;
#pragma unroll
  for (int off = 1; off < 64; off <<= 1) {
    int v = __shfl_up(s, off, 64);
    if (lane >= off) s += v;
  }
  if (lane == 63) wsum[wid] = s;
  __syncthreads();
  if (wid == 0) {
    int w = (lane < 16) ? wsum[lane] : 0;
#pragma unroll
    for (int off = 1; off < 16; off <<= 1) {
      int v = __shfl_up(w, off, 64);
      if (lane >= off) w += v;
    }
    if (lane < 16) wsum[lane] = w;
  }
  __syncthreads();
  int run = ((wid > 0) ? wsum[wid - 1] : 0) + s - p;
  int4 iv;
  iv.x = m[0] ? run : -1; run += m[0];
  iv.y = m[1] ? run : -1; run += m[1];
  iv.z = m[2] ? run : -1; run += m[2];
  iv.w = m[3] ? run : -1;
  *(int4*)(inv + b * 4096 + t0) = iv;
  if (tid == 1023) lens[b] = wsum[15];
}

// ---- k_zero: fill out rows j >= lens[b] with zeros ----
__global__ __launch_bounds__(256) void k_zero(
    const char* __restrict__ wsc, float* __restrict__ out) {
  const int* lens = (const int*)(wsc + WS_LENS);
  int b = blockIdx.y;
  int j = blockIdx.x * 4 + (threadIdx.x >> 6);
  if (j < lens[b]) return;
  int lane = threadIdx.x & 63;
  float4 z = {0.f, 0.f, 0.f, 0.f};
  float* op = out + ((size_t)(b * 4096 + j)) * 512 + lane * 8;
  *(float4*)op = z;
  *(float4*)(op + 4) = z;
}

// ---- k_gemm v6: DENSE m97-style LDS-staged bf16 MFMA + scatter epilogue ----
#define BM 128
#define BN 128
#define BK 32

__global__ __launch_bounds__(256) void k_gemm(
    const uint16_t* __restrict__ Abf, const float* __restrict__ be,
    const char* __restrict__ wsc, float* __restrict__ out) {
  const uint16_t* Wt = (const uint16_t*)(wsc + WS_WT);
  const int* inv = (const int*)(wsc + WS_INV);

  int g0 = blockIdx.x * BM;       // global row base (8*4096 rows total)
  int nb = blockIdx.y;
  int b = g0 >> 12;
  int tid = threadIdx.x;
  int wave = tid >> 6, lane = tid & 63;
  int wm = wave & 1, wn = wave >> 1;
  int quad = lane >> 4, l15 = lane & 15;
  int srow = lane >> 2;
  int scol = (lane & 3) * 8;

  __shared__ __align__(16) uint16_t As[BM * BK];
  __shared__ __align__(16) uint16_t Bs[BN * BK];

  f32x4 acc[4][4] = {};

  const uint16_t* gA = Abf + (size_t)g0 * 512;
  const uint16_t* gB = Wt + (size_t)(nb * BN) * 512;
  uint16_t* lA = As + (size_t)(wave * 16) * BK;  // wave-uniform LDS base
  uint16_t* lB = Bs + (size_t)(wave * 16) * BK;

  for (int k0 = 0; k0 < 512; k0 += BK) {
    gld_lds16(gA + (size_t)(wave * 16 + srow) * 512 + k0 + scol, lA);
    gld_lds16(gA + (size_t)(64 + wave * 16 + srow) * 512 + k0 + scol, lA + 64 * BK);
    gld_lds16(gB + (size_t)(wave * 16 + srow) * 512 + k0 + scol, lB);
    gld_lds16(gB + (size_t)(64 + wave * 16 + srow) * 512 + k0 + scol, lB + 64 * BK);
    __syncthreads();

    short8 af[4], bfr[4];
#pragma unroll
    for (int mi = 0; mi < 4; ++mi)
      af[mi] = *(const short8*)&As[(wm * 64 + mi * 16 + l15) * BK + quad * 8];
#pragma unroll
    for (int ni = 0; ni < 4; ++ni)
      bfr[ni] = *(const short8*)&Bs[(wn * 64 + ni * 16 + l15) * BK + quad * 8];
#pragma unroll
    for (int mi = 0; mi < 4; ++mi)
#pragma unroll
      for (int ni = 0; ni < 4; ++ni)
        acc[mi][ni] = __builtin_amdgcn_mfma_f32_16x16x32_bf16(af[mi], bfr[ni], acc[mi][ni], 0, 0, 0);
    __syncthreads();
  }

  // preload this block's 128 inv entries into LDS (As is dead now)
  int* invs = (int*)As;
  if (tid < 128) invs[tid] = inv[g0 + tid];
  __syncthreads();

  // scatter epilogue: selected rows -> out[b][pj][:], 8*(acc + be + pe(t,n))
  const float c1 = -0.01798894603951557739f;  // -ln(10000)/512
#pragma unroll
  for (int ni = 0; ni < 4; ++ni) {
    int n = nb * BN + wn * 64 + ni * 16 + l15;
    float dv = __expf((float)(n & ~1) * c1);
    float ben = be[n];
#pragma unroll
    for (int mi = 0; mi < 4; ++mi) {
#pragma unroll
      for (int r = 0; r < 4; ++r) {
        int lrow = wm * 64 + mi * 16 + quad * 4 + r;
        int pj = invs[lrow];
        if (pj >= 0) {
          int t = (g0 + lrow) & 4095;
          float ph = (float)t * dv;
          float pe = (n & 1) ? __cosf(ph) : __sinf(ph);
          out[((size_t)(b * 4096 + pj)) * 512 + n] = 8.0f * (acc[mi][ni][r] + ben + pe);
        }
      }
    }
  }
}

extern "C" void kernel_launch(void* const* d_in, const int* in_sizes, int n_in,
                              void* d_out, int out_size, void* d_ws, size_t ws_size,
                              hipStream_t stream) {
  const float* data = (const float*)d_in[0];
  const float* v0   = (const float*)d_in[1];
  const float* v1   = (const float*)d_in[2];
  const float* W    = (const float*)d_in[3];
  const float* be   = (const float*)d_in[4];
  const float* Wx   = (const float*)d_in[5];
  const float* Wv   = (const float*)d_in[6];
  const float* bfp  = (const float*)d_in[7];
  char* ws = (char*)d_ws;
  float* out = (float*)d_out;
  uint16_t* Abf = (uint16_t*)(ws + WS_ABF16);

  hipLaunchKernelGGL(k_prep0, dim3(1), dim3(64), 0, stream, ws);
  hipLaunchKernelGGL(k_prep, dim3(5136), dim3(64), 0, stream, v0, v1, W, be, Wx, Wv, ws);
  hipLaunchKernelGGL(k_dot, dim3(8192), dim3(256), 0, stream,
                     data, bfp, (const char*)ws, (int*)(ws + WS_MASK), Abf);
  hipLaunchKernelGGL(k_scan, dim3(8), dim3(1024), 0, stream,
                     (const int*)(ws + WS_MASK), (int*)(ws + WS_INV), (int*)(ws + WS_LENS));
  hipLaunchKernelGGL(k_zero, dim3(1024, 8), dim3(256), 0, stream, (const char*)ws, out);
  hipLaunchKernelGGL(k_gemm, dim3(256, 4), dim3(256), 0, stream,
                     Abf, be, (const char*)ws, out);
}